// Round 16
// baseline (474.687 us; speedup 1.0000x reference)
//
#include <hip/hip_runtime.h>
#include <hip/hip_bf16.h>

// ---------------------------------------------------------------------------
// GCN via device-built CSR, all tensors bf16, all GEMMs MFMA:
//   k_wt: W1..W3 -> WT bf16 [n][k]; Wlin -> WTL bf16 [n][384]
//   mega0 = [gemm1 MFMA (f32 x -> bf16 in staging) | deg count (padded)]
//   scan1 ; scan3f (fused scan2+3) ; k_fill (pure, no LDS, padded cursor)
//   3x [ agg -> hcat bf16 ; gemm_{k+1} MFMA ] ; final MFMA
// Contention fixes: cursor/deg counters padded to 1 per 64B line (16x less
// cross-XCD line ping-pong); fill kernel has no LDS -> 8 blocks/CU.
// MFMA: mfma_f32_32x32x16_bf16, LDS XOR swizzle byte^=(row&7)<<4,
// C/D map col=lane&31, row=(q&3)+8*(q>>2)+4*(lane>>5) [verified r13/r14].
// ---------------------------------------------------------------------------

typedef __attribute__((ext_vector_type(8))) short bf16x8;
typedef __attribute__((ext_vector_type(16))) float f32x16;

__device__ __forceinline__ unsigned short f2bf(float f) {  // RNE f32->bf16
  unsigned int u = __float_as_uint(f);
  u += 0x7FFFu + ((u >> 16) & 1u);
  return (unsigned short)(u >> 16);
}
__device__ __forceinline__ unsigned int bfpack(float a, float b) {
  return ((unsigned int)f2bf(a)) | ((unsigned int)f2bf(b) << 16);
}
__device__ __forceinline__ void bf4_unpack(uint2 v, float* f) {
  f[0] = __uint_as_float(v.x << 16); f[1] = __uint_as_float(v.x & 0xFFFF0000u);
  f[2] = __uint_as_float(v.y << 16); f[3] = __uint_as_float(v.y & 0xFFFF0000u);
}

// ---- weight transposes: W1..W3 -> WT[128][128]; Wlin -> WTL[64][384] ------
__global__ __launch_bounds__(256) void k_wt(
    const float* __restrict__ W1, const float* __restrict__ W2,
    const float* __restrict__ W3, const float* __restrict__ Wlin,
    unsigned short* __restrict__ WT1, unsigned short* __restrict__ WT2,
    unsigned short* __restrict__ WT3, unsigned short* __restrict__ WTL) {
  const int idx = blockIdx.x * 256 + threadIdx.x;  // 49152 + 24576
  if (idx < 49152) {
    const int w = idx >> 14;
    const int rem = idx & 16383;
    const int n = rem >> 7, k = rem & 127;
    const float* W = (w == 0) ? W1 : (w == 1) ? W2 : W3;
    unsigned short* WT = (w == 0) ? WT1 : (w == 1) ? WT2 : WT3;
    WT[n * 128 + k] = f2bf(W[k * 128 + n]);
  } else if (idx < 49152 + 24576) {
    const int rem = idx - 49152;
    const int n = rem / 384, k = rem - n * 384;
    WTL[n * 384 + k] = f2bf(Wlin[k * 64 + n]);
  }
}

// ---- MFMA GEMM body, f32 A input (convert in staging), BK=64 --------------
__device__ __forceinline__ void gemm_mfma_f32in_body(
    const float* __restrict__ A, const unsigned short* __restrict__ WT,
    unsigned short* __restrict__ hw, int N, int n0, char* hsb, char* wsb) {
  const int tid = threadIdx.x;
  const int rows = min(128, N - n0);
  const int l = tid & 63;
  const int m0 = (tid >> 6) << 5;
  const int lm = l & 31;
  const int lkb = (l >> 5) << 4;       // K byte sub-offset: 0 or 16
  const int ra = m0 + lm;
  f32x16 acc[4];
  #pragma unroll
  for (int t = 0; t < 4; ++t)
    #pragma unroll
    for (int q = 0; q < 16; ++q) acc[t][q] = 0.f;

  for (int kc = 0; kc < 128; kc += 64) {
    #pragma unroll
    for (int u = 0; u < 4; ++u) {     // stage A chunk: 128 rows x 64 K, f32->bf16
      const int i = tid + 256 * u;
      const int r = i >> 3, k8 = (i & 7) << 3;
      uint4 o = make_uint4(0u, 0u, 0u, 0u);
      if (r < rows) {
        const float* ap = A + (size_t)(n0 + r) * 128 + kc + k8;
        const float4 a = *(const float4*)(ap);
        const float4 b = *(const float4*)(ap + 4);
        o.x = bfpack(a.x, a.y); o.y = bfpack(a.z, a.w);
        o.z = bfpack(b.x, b.y); o.w = bfpack(b.z, b.w);
      }
      *(uint4*)(hsb + ((r * 128 + k8 * 2) ^ ((r & 7) << 4))) = o;
    }
    #pragma unroll
    for (int u = 0; u < 4; ++u) {     // stage WT chunk: 128 n x 64 K (bf16)
      const int i = tid + 256 * u;
      const int nn = i >> 3, k8 = (i & 7) << 3;
      const uint4 v = *(const uint4*)(WT + nn * 128 + kc + k8);
      *(uint4*)(wsb + ((nn * 128 + k8 * 2) ^ ((nn & 7) << 4))) = v;
    }
    __syncthreads();
    #pragma unroll
    for (int ks = 0; ks < 4; ++ks) {
      const int kb = ks * 32 + lkb;
      const bf16x8 af = *(const bf16x8*)(hsb + ((ra * 128 + kb) ^ ((ra & 7) << 4)));
      #pragma unroll
      for (int t = 0; t < 4; ++t) {
        const int rb = t * 32 + lm;
        const bf16x8 bfr = *(const bf16x8*)(wsb + ((rb * 128 + kb) ^ ((rb & 7) << 4)));
        acc[t] = __builtin_amdgcn_mfma_f32_32x32x16_bf16(af, bfr, acc[t], 0, 0, 0);
      }
    }
    __syncthreads();
  }

  #pragma unroll
  for (int t = 0; t < 4; ++t) {
    #pragma unroll
    for (int q = 0; q < 16; ++q) {
      const int m = m0 + (q & 3) + ((q >> 2) << 3) + ((l >> 5) << 2);
      if (m < rows) hw[(size_t)(n0 + m) * 128 + t * 32 + lm] = f2bf(acc[t][q]);
    }
  }
}

// ---- mega0: [gemm1 MFMA (blocks first) | degree count, padded] ------------
__global__ __launch_bounds__(256, 2) void k_mega0(
    const float* __restrict__ x, const unsigned short* __restrict__ WT1,
    unsigned short* __restrict__ hw, int N, int gb,
    const int* __restrict__ coli, int E, int* __restrict__ degi_pad) {
  __shared__ __align__(16) unsigned short hs[128 * 64];   // 16KB
  __shared__ __align__(16) unsigned short wsm[128 * 64];  // 16KB
  if ((int)blockIdx.x < gb) {
    gemm_mfma_f32in_body(x, WT1, hw, N, blockIdx.x * 128, (char*)hs, (char*)wsm);
  } else {
    const int b = blockIdx.x - gb;
    #pragma unroll
    for (int h = 0; h < 2; ++h) {
      const int base = b * 2048 + h * 1024 + (int)threadIdx.x * 4;
      if (base + 3 < E) {
        const int4 c4 = *(const int4*)(coli + base);
        atomicAdd(&degi_pad[c4.x * 16], 1); atomicAdd(&degi_pad[c4.y * 16], 1);
        atomicAdd(&degi_pad[c4.z * 16], 1); atomicAdd(&degi_pad[c4.w * 16], 1);
      } else {
        for (int e = base; e < E; ++e) atomicAdd(&degi_pad[coli[e] * 16], 1);
      }
    }
  }
}

// ---- scan1: padded deg -> dense degc + dinv + block-local offs + bsums ----
__global__ __launch_bounds__(256) void k_scan1(
    const int* __restrict__ degi_pad, int N, int* __restrict__ degc,
    int* __restrict__ offs, int* __restrict__ bsums, float* __restrict__ dinv) {
  __shared__ int sm[256];
  const int b = blockIdx.x, t = threadIdx.x;
  const int base = b * 1024 + t * 4;
  int v[4];
  #pragma unroll
  for (int i = 0; i < 4; ++i)
    v[i] = (base + i < N) ? degi_pad[(base + i) * 16] : 0;
  #pragma unroll
  for (int i = 0; i < 4; ++i)
    if (base + i < N) {
      degc[base + i] = v[i];
      dinv[base + i] = rsqrtf(1.0f + (float)v[i]);
    }
  const int s = v[0] + v[1] + v[2] + v[3];
  sm[t] = s;
  __syncthreads();
  for (int ofs = 1; ofs < 256; ofs <<= 1) {
    const int add = (t >= ofs) ? sm[t - ofs] : 0;
    __syncthreads();
    sm[t] += add;
    __syncthreads();
  }
  if (t == 255) bsums[b] = sm[255];
  int run = sm[t] - s;
  #pragma unroll
  for (int i = 0; i < 4; ++i) {
    if (base + i < N) offs[base + i] = run;
    run += v[i];
  }
}

// ---- scan3f (fused scan2+3): global offsets + padded cursor init ----------
__global__ __launch_bounds__(256) void k_scan3f(
    int* __restrict__ offs, const int* __restrict__ bsums,
    int* __restrict__ cursor_pad, int nb, int N) {
  __shared__ int sm[128];
  const int t = threadIdx.x;
  if (t < 128) sm[t] = (t < nb) ? bsums[t] : 0;
  __syncthreads();
  for (int ofs = 1; ofs < 128; ofs <<= 1) {
    int add = 0;
    if (t < 128 && t >= ofs) add = sm[t - ofs];
    __syncthreads();
    if (t < 128) sm[t] += add;
    __syncthreads();
  }
  const int add = (blockIdx.x == 0) ? 0 : sm[blockIdx.x - 1];
  const int base = blockIdx.x * 1024 + t * 4;
  #pragma unroll
  for (int i = 0; i < 4; ++i) {
    const int idx = base + i;
    if (idx < N) {
      const int o = offs[idx] + add;
      offs[idx] = o;
      cursor_pad[idx * 16] = o;
    }
  }
}

// ---- fill: pure scatter, no LDS (8 blocks/CU), padded cursor --------------
__global__ __launch_bounds__(256) void k_fill(
    const int* __restrict__ rowi, const int* __restrict__ coli,
    int* __restrict__ cursor_pad, int* __restrict__ sorted_row, int E) {
  const int base = blockIdx.x * 1024 + (int)threadIdx.x * 4;
  if (base + 3 < E) {
    const int4 c4 = *(const int4*)(coli + base);
    const int4 r4 = *(const int4*)(rowi + base);
    int p;
    p = atomicAdd(&cursor_pad[c4.x * 16], 1); __builtin_nontemporal_store(r4.x, &sorted_row[p]);
    p = atomicAdd(&cursor_pad[c4.y * 16], 1); __builtin_nontemporal_store(r4.y, &sorted_row[p]);
    p = atomicAdd(&cursor_pad[c4.z * 16], 1); __builtin_nontemporal_store(r4.z, &sorted_row[p]);
    p = atomicAdd(&cursor_pad[c4.w * 16], 1); __builtin_nontemporal_store(r4.w, &sorted_row[p]);
  } else {
    for (int e = base; e < E; ++e) {
      const int p = atomicAdd(&cursor_pad[coli[e] * 16], 1);
      __builtin_nontemporal_store(rowi[e], &sorted_row[p]);
    }
  }
}

// ---- MFMA GEMM (layers 2,3): full-K 64KB LDS (proven r13) -----------------
__global__ __launch_bounds__(256, 2) void k_gemm_mfma(
    const unsigned short* __restrict__ A, long long lda,
    const unsigned short* __restrict__ WT, unsigned short* __restrict__ hw,
    int N) {
  __shared__ __align__(16) unsigned short hs[128 * 128];
  __shared__ __align__(16) unsigned short WsT[128 * 128];
  const int tid = threadIdx.x;
  const int n0 = blockIdx.x * 128;
  const int rows = min(128, N - n0);
  char* hsb = (char*)hs;
  char* wsb = (char*)WsT;

  #pragma unroll
  for (int u = 0; u < 8; ++u) {
    const int i = tid + 256 * u;
    const int r = i >> 4, k8 = (i & 15) << 3;
    uint4 v = make_uint4(0u, 0u, 0u, 0u);
    if (r < rows) v = *(const uint4*)(A + (size_t)(n0 + r) * lda + k8);
    *(uint4*)(hsb + ((r * 256 + k8 * 2) ^ ((r & 7) << 4))) = v;
  }
  #pragma unroll
  for (int u = 0; u < 8; ++u) {
    const int i = tid + 256 * u;
    const int nn = i >> 4, k8 = (i & 15) << 3;
    const uint4 v = *(const uint4*)(WT + nn * 128 + k8);
    *(uint4*)(wsb + ((nn * 256 + k8 * 2) ^ ((nn & 7) << 4))) = v;
  }
  __syncthreads();

  const int l = tid & 63;
  const int m0 = (tid >> 6) << 5;
  const int lm = l & 31;
  const int lk = (l >> 5) << 3;
  const int ra = m0 + lm;
  f32x16 acc[4];
  #pragma unroll
  for (int t = 0; t < 4; ++t)
    #pragma unroll
    for (int q = 0; q < 16; ++q) acc[t][q] = 0.f;

  #pragma unroll
  for (int ks = 0; ks < 8; ++ks) {
    const int kb = (ks * 16 + lk) * 2;
    const bf16x8 af = *(const bf16x8*)(hsb + ((ra * 256 + kb) ^ ((ra & 7) << 4)));
    #pragma unroll
    for (int t = 0; t < 4; ++t) {
      const int rb = t * 32 + lm;
      const bf16x8 bfr = *(const bf16x8*)(wsb + ((rb * 256 + kb) ^ ((rb & 7) << 4)));
      acc[t] = __builtin_amdgcn_mfma_f32_32x32x16_bf16(af, bfr, acc[t], 0, 0, 0);
    }
  }

  #pragma unroll
  for (int t = 0; t < 4; ++t) {
    #pragma unroll
    for (int q = 0; q < 16; ++q) {
      const int m = m0 + (q & 3) + ((q >> 2) << 3) + ((l >> 5) << 2);
      if (m < rows) hw[(size_t)(n0 + m) * 128 + t * 32 + lm] = f2bf(acc[t][q]);
    }
  }
}

// ---- MFMA final: out = hcat(bf16) @ Wlin + blin, 3 K-chunks of 128 --------
__global__ __launch_bounds__(256, 2) void k_final_mfma(
    const unsigned short* __restrict__ hcat, const unsigned short* __restrict__ WTL,
    const float* __restrict__ blin, float* __restrict__ out, int N) {
  __shared__ __align__(16) unsigned short hs[128 * 128];
  __shared__ __align__(16) unsigned short WsT[64 * 128];
  const int tid = threadIdx.x;
  const int n0 = blockIdx.x * 128;
  const int rows = min(128, N - n0);
  char* hsb = (char*)hs;
  char* wsb = (char*)WsT;

  const int l = tid & 63;
  const int m0 = (tid >> 6) << 5;
  const int lm = l & 31;
  const int lk = (l >> 5) << 3;
  const int ra = m0 + lm;
  f32x16 acc[2];
  #pragma unroll
  for (int t = 0; t < 2; ++t)
    #pragma unroll
    for (int q = 0; q < 16; ++q) acc[t][q] = 0.f;

  for (int kc = 0; kc < 384; kc += 128) {
    #pragma unroll
    for (int u = 0; u < 8; ++u) {
      const int i = tid + 256 * u;
      const int r = i >> 4, k8 = (i & 15) << 3;
      uint4 v = make_uint4(0u, 0u, 0u, 0u);
      if (r < rows) v = *(const uint4*)(hcat + (size_t)(n0 + r) * 384 + kc + k8);
      *(uint4*)(hsb + ((r * 256 + k8 * 2) ^ ((r & 7) << 4))) = v;
    }
    #pragma unroll
    for (int u = 0; u < 4; ++u) {
      const int i = tid + 256 * u;
      const int nn = i >> 4, k8 = (i & 15) << 3;
      const uint4 v = *(const uint4*)(WTL + nn * 384 + kc + k8);
      *(uint4*)(wsb + ((nn * 256 + k8 * 2) ^ ((nn & 7) << 4))) = v;
    }
    __syncthreads();

    #pragma unroll
    for (int ks = 0; ks < 8; ++ks) {
      const int kb = (ks * 16 + lk) * 2;
      const bf16x8 af = *(const bf16x8*)(hsb + ((ra * 256 + kb) ^ ((ra & 7) << 4)));
      #pragma unroll
      for (int t = 0; t < 2; ++t) {
        const int rb = t * 32 + lm;
        const bf16x8 bfr = *(const bf16x8*)(wsb + ((rb * 256 + kb) ^ ((rb & 7) << 4)));
        acc[t] = __builtin_amdgcn_mfma_f32_32x32x16_bf16(af, bfr, acc[t], 0, 0, 0);
      }
    }
    __syncthreads();
  }

  #pragma unroll
  for (int t = 0; t < 2; ++t) {
    const float bb = blin[t * 32 + lm];
    #pragma unroll
    for (int q = 0; q < 16; ++q) {
      const int m = m0 + (q & 3) + ((q >> 2) << 3) + ((l >> 5) << 2);
      if (m < rows) out[(size_t)(n0 + m) * 64 + t * 32 + lm] = acc[t][q] + bb;
    }
  }
}

// ---- segment aggregate (32 lanes/node, ushort4/lane, 8-deep gather) -------
__global__ __launch_bounds__(256) void k_agg(
    const int* __restrict__ offs, const int* __restrict__ degc,
    const int* __restrict__ sorted_row, const float* __restrict__ dinv,
    const unsigned short* __restrict__ hw, const float* __restrict__ bias,
    unsigned short* __restrict__ hcat, int koff, int N) {
  const int g = (int)((blockIdx.x * 256 + threadIdx.x) >> 5);
  if (g >= N) return;
  const int j = (threadIdx.x & 31) << 2;
  const float dc = dinv[g];
  float acc[4];
  {
    const uint2 sv = *(const uint2*)(hw + (size_t)g * 128 + j);
    float f[4];
    bf4_unpack(sv, f);
    #pragma unroll
    for (int q = 0; q < 4; ++q) acc[q] = dc * f[q];
  }

  const int off = offs[g];
  const int end = off + degc[g];
  int e = off;
  for (; e + 7 < end; e += 8) {
    int r[8];
    #pragma unroll
    for (int t = 0; t < 8; ++t) r[t] = sorted_row[e + t];
    float dr[8];
    uint2 v[8];
    #pragma unroll
    for (int t = 0; t < 8; ++t) {
      dr[t] = dinv[r[t]];
      v[t] = *(const uint2*)(hw + (size_t)r[t] * 128 + j);
    }
    #pragma unroll
    for (int t = 0; t < 8; ++t) {
      float f[4];
      bf4_unpack(v[t], f);
      #pragma unroll
      for (int q = 0; q < 4; ++q) acc[q] = fmaf(dr[t], f[q], acc[q]);
    }
  }
  for (; e + 3 < end; e += 4) {
    int r[4];
    #pragma unroll
    for (int t = 0; t < 4; ++t) r[t] = sorted_row[e + t];
    float dr[4];
    uint2 v[4];
    #pragma unroll
    for (int t = 0; t < 4; ++t) {
      dr[t] = dinv[r[t]];
      v[t] = *(const uint2*)(hw + (size_t)r[t] * 128 + j);
    }
    #pragma unroll
    for (int t = 0; t < 4; ++t) {
      float f[4];
      bf4_unpack(v[t], f);
      #pragma unroll
      for (int q = 0; q < 4; ++q) acc[q] = fmaf(dr[t], f[q], acc[q]);
    }
  }
  for (; e < end; ++e) {
    const int r0 = sorted_row[e];
    const float d0 = dinv[r0];
    const uint2 v0 = *(const uint2*)(hw + (size_t)r0 * 128 + j);
    float f[4];
    bf4_unpack(v0, f);
    #pragma unroll
    for (int q = 0; q < 4; ++q) acc[q] = fmaf(d0, f[q], acc[q]);
  }

  const float4 bb = *(const float4*)(bias + j);
  const float o0 = fmaxf(fmaf(dc, acc[0], bb.x), 0.f);
  const float o1 = fmaxf(fmaf(dc, acc[1], bb.y), 0.f);
  const float o2 = fmaxf(fmaf(dc, acc[2], bb.z), 0.f);
  const float o3 = fmaxf(fmaf(dc, acc[3], bb.w), 0.f);
  uint2 st;
  st.x = bfpack(o0, o1);
  st.y = bfpack(o2, o3);
  *(uint2*)(hcat + (size_t)g * 384 + koff + j) = st;
}

extern "C" void kernel_launch(void* const* d_in, const int* in_sizes, int n_in,
                              void* d_out, int out_size, void* d_ws, size_t ws_size,
                              hipStream_t stream) {
  const float* x    = (const float*)d_in[0];
  const int*   ei   = (const int*)d_in[1];
  const float* W1   = (const float*)d_in[2];
  const float* b1   = (const float*)d_in[3];
  const float* W2   = (const float*)d_in[4];
  const float* b2   = (const float*)d_in[5];
  const float* W3   = (const float*)d_in[6];
  const float* b3   = (const float*)d_in[7];
  const float* Wlin = (const float*)d_in[8];
  const float* blin = (const float*)d_in[9];

  const int N = in_sizes[0] / 128;
  const int E = in_sizes[1] / 2;
  const int* rowi = ei;
  const int* coli = ei + E;

  // ws: degi_pad | cursor_pad | degc | dinv | offs | bsums | sorted_row |
  //     WT1 | WT2 | WT3 | WTL | hw | hcat
  char* ws = (char*)d_ws;
  const size_t nb4  = (((size_t)N * 4) + 255) & ~(size_t)255;
  const size_t nb64 = (((size_t)N * 64) + 255) & ~(size_t)255;
  int*   degi_pad   = (int*)ws;                 ws += nb64;
  int*   cursor_pad = (int*)ws;                 ws += nb64;
  int*   degc       = (int*)ws;                 ws += nb4;
  float* dinv       = (float*)ws;               ws += nb4;
  int*   offs       = (int*)ws;                 ws += nb4;
  int*   bsums      = (int*)ws;                 ws += 1024;
  int*   sorted_row = (int*)ws;                 ws += (((size_t)E * 4) + 255) & ~(size_t)255;
  unsigned short* WT1  = (unsigned short*)ws;   ws += 128 * 128 * 2;
  unsigned short* WT2  = (unsigned short*)ws;   ws += 128 * 128 * 2;
  unsigned short* WT3  = (unsigned short*)ws;   ws += 128 * 128 * 2;
  unsigned short* WTL  = (unsigned short*)ws;   ws += 64 * 384 * 2;
  unsigned short* hw   = (unsigned short*)ws;   ws += (size_t)N * 128 * 2;
  unsigned short* hcat = (unsigned short*)ws;

  const int nblk = (N + 1023) / 1024;  // <= 128
  const int gemmBlocks = (N + 127) / 128;
  const int degBlocks  = (E + 2047) / 2048;
  const int fillBlocks = (E + 1023) / 1024;
  const int aggBlocks  = (N + 7) / 8;

  k_wt<<<(49152 + 24576 + 255) / 256, 256, 0, stream>>>(W1, W2, W3, Wlin,
                                                        WT1, WT2, WT3, WTL);
  hipMemsetAsync(degi_pad, 0, (size_t)N * 64, stream);
  k_mega0<<<gemmBlocks + degBlocks, 256, 0, stream>>>(x, WT1, hw, N, gemmBlocks,
                                                      coli, E, degi_pad);
  k_scan1<<<nblk, 256, 0, stream>>>(degi_pad, N, degc, offs, bsums, dinv);
  k_scan3f<<<nblk, 256, 0, stream>>>(offs, bsums, cursor_pad, nblk, N);
  k_fill<<<fillBlocks, 256, 0, stream>>>(rowi, coli, cursor_pad, sorted_row, E);

  k_agg<<<aggBlocks, 256, 0, stream>>>(offs, degc, sorted_row, dinv, hw,
                                       b1, hcat, 0, N);
  k_gemm_mfma<<<gemmBlocks, 256, 0, stream>>>(hcat, 384, WT2, hw, N);
  k_agg<<<aggBlocks, 256, 0, stream>>>(offs, degc, sorted_row, dinv, hw,
                                       b2, hcat, 128, N);
  k_gemm_mfma<<<gemmBlocks, 256, 0, stream>>>(hcat + 128, 384, WT3, hw, N);
  k_agg<<<aggBlocks, 256, 0, stream>>>(offs, degc, sorted_row, dinv, hw,
                                       b3, hcat, 256, N);
  k_final_mfma<<<gemmBlocks, 256, 0, stream>>>(hcat, WTL, blin, (float*)d_out, N);
}

// Round 17
// 419.210 us; speedup vs baseline: 1.1323x; 1.1323x over previous
//
#include <hip/hip_runtime.h>
#include <hip/hip_bf16.h>

// ---------------------------------------------------------------------------
// GCN via device-built CSR, all tensors bf16, all GEMMs MFMA.
//   k_wt: W1..W3 -> WT bf16 [n][k]; Wlin -> WTL bf16 [n][384]
//   mega0 = [gemm1 MFMA (f32 x -> bf16 in staging) | deg, XCD-partitioned]
//   scan1 ; scan3f ; k_fill (XCD-partitioned scatter)
//   3x [ agg -> hcat bf16 ; gemm_{k+1} MFMA ] ; final MFMA
// XCD partition (r17): cols split into 8 ranges; block handles range
// blockIdx%8 (presumed XCD via round-robin dispatch) reading the whole edge
// stream (8x coalesced re-read ~17us) -> every cursor/deg/sorted_row line is
// written by ONE XCD -> L2 write-combining instead of 64B-line ping-pong
// (r16 isolated: 111MB WRITE = full-line writeback per 4B store).
// MFMA: mfma_f32_32x32x16_bf16, LDS XOR swizzle byte^=(row&7)<<4,
// C/D map col=lane&31, row=(q&3)+8*(q>>2)+4*(lane>>5) [verified r13/r14].
// ---------------------------------------------------------------------------

typedef __attribute__((ext_vector_type(8))) short bf16x8;
typedef __attribute__((ext_vector_type(16))) float f32x16;

__device__ __forceinline__ unsigned short f2bf(float f) {  // RNE f32->bf16
  unsigned int u = __float_as_uint(f);
  u += 0x7FFFu + ((u >> 16) & 1u);
  return (unsigned short)(u >> 16);
}
__device__ __forceinline__ unsigned int bfpack(float a, float b) {
  return ((unsigned int)f2bf(a)) | ((unsigned int)f2bf(b) << 16);
}
__device__ __forceinline__ void bf4_unpack(uint2 v, float* f) {
  f[0] = __uint_as_float(v.x << 16); f[1] = __uint_as_float(v.x & 0xFFFF0000u);
  f[2] = __uint_as_float(v.y << 16); f[3] = __uint_as_float(v.y & 0xFFFF0000u);
}

// ---- weight transposes: W1..W3 -> WT[128][128]; Wlin -> WTL[64][384] ------
__global__ __launch_bounds__(256) void k_wt(
    const float* __restrict__ W1, const float* __restrict__ W2,
    const float* __restrict__ W3, const float* __restrict__ Wlin,
    unsigned short* __restrict__ WT1, unsigned short* __restrict__ WT2,
    unsigned short* __restrict__ WT3, unsigned short* __restrict__ WTL) {
  const int idx = blockIdx.x * 256 + threadIdx.x;  // 49152 + 24576
  if (idx < 49152) {
    const int w = idx >> 14;
    const int rem = idx & 16383;
    const int n = rem >> 7, k = rem & 127;
    const float* W = (w == 0) ? W1 : (w == 1) ? W2 : W3;
    unsigned short* WT = (w == 0) ? WT1 : (w == 1) ? WT2 : WT3;
    WT[n * 128 + k] = f2bf(W[k * 128 + n]);
  } else if (idx < 49152 + 24576) {
    const int rem = idx - 49152;
    const int n = rem / 384, k = rem - n * 384;
    WTL[n * 384 + k] = f2bf(Wlin[k * 64 + n]);
  }
}

// ---- MFMA GEMM body, f32 A input (convert in staging), BK=64 --------------
__device__ __forceinline__ void gemm_mfma_f32in_body(
    const float* __restrict__ A, const unsigned short* __restrict__ WT,
    unsigned short* __restrict__ hw, int N, int n0, char* hsb, char* wsb) {
  const int tid = threadIdx.x;
  const int rows = min(128, N - n0);
  const int l = tid & 63;
  const int m0 = (tid >> 6) << 5;
  const int lm = l & 31;
  const int lkb = (l >> 5) << 4;       // K byte sub-offset: 0 or 16
  const int ra = m0 + lm;
  f32x16 acc[4];
  #pragma unroll
  for (int t = 0; t < 4; ++t)
    #pragma unroll
    for (int q = 0; q < 16; ++q) acc[t][q] = 0.f;

  for (int kc = 0; kc < 128; kc += 64) {
    #pragma unroll
    for (int u = 0; u < 4; ++u) {     // stage A chunk: 128 rows x 64 K, f32->bf16
      const int i = tid + 256 * u;
      const int r = i >> 3, k8 = (i & 7) << 3;
      uint4 o = make_uint4(0u, 0u, 0u, 0u);
      if (r < rows) {
        const float* ap = A + (size_t)(n0 + r) * 128 + kc + k8;
        const float4 a = *(const float4*)(ap);
        const float4 b = *(const float4*)(ap + 4);
        o.x = bfpack(a.x, a.y); o.y = bfpack(a.z, a.w);
        o.z = bfpack(b.x, b.y); o.w = bfpack(b.z, b.w);
      }
      *(uint4*)(hsb + ((r * 128 + k8 * 2) ^ ((r & 7) << 4))) = o;
    }
    #pragma unroll
    for (int u = 0; u < 4; ++u) {     // stage WT chunk: 128 n x 64 K (bf16)
      const int i = tid + 256 * u;
      const int nn = i >> 3, k8 = (i & 7) << 3;
      const uint4 v = *(const uint4*)(WT + nn * 128 + kc + k8);
      *(uint4*)(wsb + ((nn * 128 + k8 * 2) ^ ((nn & 7) << 4))) = v;
    }
    __syncthreads();
    #pragma unroll
    for (int ks = 0; ks < 4; ++ks) {
      const int kb = ks * 32 + lkb;
      const bf16x8 af = *(const bf16x8*)(hsb + ((ra * 128 + kb) ^ ((ra & 7) << 4)));
      #pragma unroll
      for (int t = 0; t < 4; ++t) {
        const int rb = t * 32 + lm;
        const bf16x8 bfr = *(const bf16x8*)(wsb + ((rb * 128 + kb) ^ ((rb & 7) << 4)));
        acc[t] = __builtin_amdgcn_mfma_f32_32x32x16_bf16(af, bfr, acc[t], 0, 0, 0);
      }
    }
    __syncthreads();
  }

  #pragma unroll
  for (int t = 0; t < 4; ++t) {
    #pragma unroll
    for (int q = 0; q < 16; ++q) {
      const int m = m0 + (q & 3) + ((q >> 2) << 3) + ((l >> 5) << 2);
      if (m < rows) hw[(size_t)(n0 + m) * 128 + t * 32 + lm] = f2bf(acc[t][q]);
    }
  }
}

// ---- mega0: [gemm1 MFMA (blocks first) | deg count, XCD-partitioned] ------
__global__ __launch_bounds__(256, 2) void k_mega0(
    const float* __restrict__ x, const unsigned short* __restrict__ WT1,
    unsigned short* __restrict__ hw, int N, int gb,
    const int* __restrict__ coli, int E, int* __restrict__ degi) {
  __shared__ __align__(16) unsigned short hs[128 * 64];   // 16KB
  __shared__ __align__(16) unsigned short wsm[128 * 64];  // 16KB
  if ((int)blockIdx.x < gb) {
    gemm_mfma_f32in_body(x, WT1, hw, N, blockIdx.x * 128, (char*)hs, (char*)wsm);
  } else {
    const int bb = (int)blockIdx.x - gb;
    const int xcd = (int)blockIdx.x & 7;   // presumed XCD (round-robin)
    const int chunk = bb >> 3;
    const int nsz = (N + 7) >> 3;
    const int clo = xcd * nsz;
    const int chi = min(clo + nsz, N);
    const int ebase = chunk * 8192;
    #pragma unroll
    for (int it = 0; it < 8; ++it) {
      const int e = ebase + it * 1024 + (int)threadIdx.x * 4;
      if (e + 3 < E) {
        const int4 c4 = *(const int4*)(coli + e);
        if (c4.x >= clo && c4.x < chi) atomicAdd(&degi[c4.x], 1);
        if (c4.y >= clo && c4.y < chi) atomicAdd(&degi[c4.y], 1);
        if (c4.z >= clo && c4.z < chi) atomicAdd(&degi[c4.z], 1);
        if (c4.w >= clo && c4.w < chi) atomicAdd(&degi[c4.w], 1);
      } else {
        for (int ee = e; ee < E; ++ee) {
          const int c = coli[ee];
          if (c >= clo && c < chi) atomicAdd(&degi[c], 1);
        }
      }
    }
  }
}

// ---- scan1: dense deg -> dinv + block-local offs + bsums ------------------
__global__ __launch_bounds__(256) void k_scan1(
    const int* __restrict__ degi, int N, int* __restrict__ offs,
    int* __restrict__ bsums, float* __restrict__ dinv) {
  __shared__ int sm[256];
  const int b = blockIdx.x, t = threadIdx.x;
  const int base = b * 1024 + t * 4;
  int v[4];
  #pragma unroll
  for (int i = 0; i < 4; ++i) v[i] = (base + i < N) ? degi[base + i] : 0;
  #pragma unroll
  for (int i = 0; i < 4; ++i)
    if (base + i < N) dinv[base + i] = rsqrtf(1.0f + (float)v[i]);
  const int s = v[0] + v[1] + v[2] + v[3];
  sm[t] = s;
  __syncthreads();
  for (int ofs = 1; ofs < 256; ofs <<= 1) {
    const int add = (t >= ofs) ? sm[t - ofs] : 0;
    __syncthreads();
    sm[t] += add;
    __syncthreads();
  }
  if (t == 255) bsums[b] = sm[255];
  int run = sm[t] - s;
  #pragma unroll
  for (int i = 0; i < 4; ++i) {
    if (base + i < N) offs[base + i] = run;
    run += v[i];
  }
}

// ---- scan3f (fused scan2+3): global offsets + cursor init -----------------
__global__ __launch_bounds__(256) void k_scan3f(
    int* __restrict__ offs, const int* __restrict__ bsums,
    int* __restrict__ cursor, int nb, int N) {
  __shared__ int sm[128];
  const int t = threadIdx.x;
  if (t < 128) sm[t] = (t < nb) ? bsums[t] : 0;
  __syncthreads();
  for (int ofs = 1; ofs < 128; ofs <<= 1) {
    int add = 0;
    if (t < 128 && t >= ofs) add = sm[t - ofs];
    __syncthreads();
    if (t < 128) sm[t] += add;
    __syncthreads();
  }
  const int add = (blockIdx.x == 0) ? 0 : sm[blockIdx.x - 1];
  const int base = blockIdx.x * 1024 + t * 4;
  #pragma unroll
  for (int i = 0; i < 4; ++i) {
    const int idx = base + i;
    if (idx < N) {
      const int o = offs[idx] + add;
      offs[idx] = o;
      cursor[idx] = o;
    }
  }
}

// ---- fill: XCD-partitioned scatter (plain stores -> L2 write-combining) ---
__global__ __launch_bounds__(256) void k_fill(
    const int* __restrict__ rowi, const int* __restrict__ coli,
    int* __restrict__ cursor, int* __restrict__ sorted_row, int E, int N) {
  const int xcd = (int)blockIdx.x & 7;   // presumed XCD (round-robin)
  const int chunk = (int)blockIdx.x >> 3;
  const int nsz = (N + 7) >> 3;
  const int clo = xcd * nsz;
  const int chi = min(clo + nsz, N);
  const int ebase = chunk * 8192;
  #pragma unroll
  for (int it = 0; it < 8; ++it) {
    const int e = ebase + it * 1024 + (int)threadIdx.x * 4;
    if (e + 3 < E) {
      const int4 c4 = *(const int4*)(coli + e);
      const int4 r4 = *(const int4*)(rowi + e);
      int p;
      if (c4.x >= clo && c4.x < chi) { p = atomicAdd(&cursor[c4.x], 1); sorted_row[p] = r4.x; }
      if (c4.y >= clo && c4.y < chi) { p = atomicAdd(&cursor[c4.y], 1); sorted_row[p] = r4.y; }
      if (c4.z >= clo && c4.z < chi) { p = atomicAdd(&cursor[c4.z], 1); sorted_row[p] = r4.z; }
      if (c4.w >= clo && c4.w < chi) { p = atomicAdd(&cursor[c4.w], 1); sorted_row[p] = r4.w; }
    } else {
      for (int ee = e; ee < E; ++ee) {
        const int c = coli[ee];
        if (c >= clo && c < chi) {
          const int p = atomicAdd(&cursor[c], 1);
          sorted_row[p] = rowi[ee];
        }
      }
    }
  }
}

// ---- MFMA GEMM (layers 2,3): full-K 64KB LDS (proven r13) -----------------
__global__ __launch_bounds__(256, 2) void k_gemm_mfma(
    const unsigned short* __restrict__ A, long long lda,
    const unsigned short* __restrict__ WT, unsigned short* __restrict__ hw,
    int N) {
  __shared__ __align__(16) unsigned short hs[128 * 128];
  __shared__ __align__(16) unsigned short WsT[128 * 128];
  const int tid = threadIdx.x;
  const int n0 = blockIdx.x * 128;
  const int rows = min(128, N - n0);
  char* hsb = (char*)hs;
  char* wsb = (char*)WsT;

  #pragma unroll
  for (int u = 0; u < 8; ++u) {
    const int i = tid + 256 * u;
    const int r = i >> 4, k8 = (i & 15) << 3;
    uint4 v = make_uint4(0u, 0u, 0u, 0u);
    if (r < rows) v = *(const uint4*)(A + (size_t)(n0 + r) * lda + k8);
    *(uint4*)(hsb + ((r * 256 + k8 * 2) ^ ((r & 7) << 4))) = v;
  }
  #pragma unroll
  for (int u = 0; u < 8; ++u) {
    const int i = tid + 256 * u;
    const int nn = i >> 4, k8 = (i & 15) << 3;
    const uint4 v = *(const uint4*)(WT + nn * 128 + k8);
    *(uint4*)(wsb + ((nn * 256 + k8 * 2) ^ ((nn & 7) << 4))) = v;
  }
  __syncthreads();

  const int l = tid & 63;
  const int m0 = (tid >> 6) << 5;
  const int lm = l & 31;
  const int lk = (l >> 5) << 3;
  const int ra = m0 + lm;
  f32x16 acc[4];
  #pragma unroll
  for (int t = 0; t < 4; ++t)
    #pragma unroll
    for (int q = 0; q < 16; ++q) acc[t][q] = 0.f;

  #pragma unroll
  for (int ks = 0; ks < 8; ++ks) {
    const int kb = (ks * 16 + lk) * 2;
    const bf16x8 af = *(const bf16x8*)(hsb + ((ra * 256 + kb) ^ ((ra & 7) << 4)));
    #pragma unroll
    for (int t = 0; t < 4; ++t) {
      const int rb = t * 32 + lm;
      const bf16x8 bfr = *(const bf16x8*)(wsb + ((rb * 256 + kb) ^ ((rb & 7) << 4)));
      acc[t] = __builtin_amdgcn_mfma_f32_32x32x16_bf16(af, bfr, acc[t], 0, 0, 0);
    }
  }

  #pragma unroll
  for (int t = 0; t < 4; ++t) {
    #pragma unroll
    for (int q = 0; q < 16; ++q) {
      const int m = m0 + (q & 3) + ((q >> 2) << 3) + ((l >> 5) << 2);
      if (m < rows) hw[(size_t)(n0 + m) * 128 + t * 32 + lm] = f2bf(acc[t][q]);
    }
  }
}

// ---- MFMA final: out = hcat(bf16) @ Wlin + blin, 3 K-chunks of 128 --------
__global__ __launch_bounds__(256, 2) void k_final_mfma(
    const unsigned short* __restrict__ hcat, const unsigned short* __restrict__ WTL,
    const float* __restrict__ blin, float* __restrict__ out, int N) {
  __shared__ __align__(16) unsigned short hs[128 * 128];
  __shared__ __align__(16) unsigned short WsT[64 * 128];
  const int tid = threadIdx.x;
  const int n0 = blockIdx.x * 128;
  const int rows = min(128, N - n0);
  char* hsb = (char*)hs;
  char* wsb = (char*)WsT;

  const int l = tid & 63;
  const int m0 = (tid >> 6) << 5;
  const int lm = l & 31;
  const int lk = (l >> 5) << 3;
  const int ra = m0 + lm;
  f32x16 acc[2];
  #pragma unroll
  for (int t = 0; t < 2; ++t)
    #pragma unroll
    for (int q = 0; q < 16; ++q) acc[t][q] = 0.f;

  for (int kc = 0; kc < 384; kc += 128) {
    #pragma unroll
    for (int u = 0; u < 8; ++u) {
      const int i = tid + 256 * u;
      const int r = i >> 4, k8 = (i & 15) << 3;
      uint4 v = make_uint4(0u, 0u, 0u, 0u);
      if (r < rows) v = *(const uint4*)(hcat + (size_t)(n0 + r) * 384 + kc + k8);
      *(uint4*)(hsb + ((r * 256 + k8 * 2) ^ ((r & 7) << 4))) = v;
    }
    #pragma unroll
    for (int u = 0; u < 4; ++u) {
      const int i = tid + 256 * u;
      const int nn = i >> 4, k8 = (i & 15) << 3;
      const uint4 v = *(const uint4*)(WTL + nn * 384 + kc + k8);
      *(uint4*)(wsb + ((nn * 256 + k8 * 2) ^ ((nn & 7) << 4))) = v;
    }
    __syncthreads();

    #pragma unroll
    for (int ks = 0; ks < 8; ++ks) {
      const int kb = (ks * 16 + lk) * 2;
      const bf16x8 af = *(const bf16x8*)(hsb + ((ra * 256 + kb) ^ ((ra & 7) << 4)));
      #pragma unroll
      for (int t = 0; t < 2; ++t) {
        const int rb = t * 32 + lm;
        const bf16x8 bfr = *(const bf16x8*)(wsb + ((rb * 256 + kb) ^ ((rb & 7) << 4)));
        acc[t] = __builtin_amdgcn_mfma_f32_32x32x16_bf16(af, bfr, acc[t], 0, 0, 0);
      }
    }
    __syncthreads();
  }

  #pragma unroll
  for (int t = 0; t < 2; ++t) {
    const float bb = blin[t * 32 + lm];
    #pragma unroll
    for (int q = 0; q < 16; ++q) {
      const int m = m0 + (q & 3) + ((q >> 2) << 3) + ((l >> 5) << 2);
      if (m < rows) out[(size_t)(n0 + m) * 64 + t * 32 + lm] = acc[t][q] + bb;
    }
  }
}

// ---- segment aggregate (32 lanes/node, ushort4/lane, 8-deep gather) -------
__global__ __launch_bounds__(256) void k_agg(
    const int* __restrict__ offs, const int* __restrict__ degi,
    const int* __restrict__ sorted_row, const float* __restrict__ dinv,
    const unsigned short* __restrict__ hw, const float* __restrict__ bias,
    unsigned short* __restrict__ hcat, int koff, int N) {
  const int g = (int)((blockIdx.x * 256 + threadIdx.x) >> 5);
  if (g >= N) return;
  const int j = (threadIdx.x & 31) << 2;
  const float dc = dinv[g];
  float acc[4];
  {
    const uint2 sv = *(const uint2*)(hw + (size_t)g * 128 + j);
    float f[4];
    bf4_unpack(sv, f);
    #pragma unroll
    for (int q = 0; q < 4; ++q) acc[q] = dc * f[q];
  }

  const int off = offs[g];
  const int end = off + degi[g];
  int e = off;
  for (; e + 7 < end; e += 8) {
    int r[8];
    #pragma unroll
    for (int t = 0; t < 8; ++t) r[t] = sorted_row[e + t];
    float dr[8];
    uint2 v[8];
    #pragma unroll
    for (int t = 0; t < 8; ++t) {
      dr[t] = dinv[r[t]];
      v[t] = *(const uint2*)(hw + (size_t)r[t] * 128 + j);
    }
    #pragma unroll
    for (int t = 0; t < 8; ++t) {
      float f[4];
      bf4_unpack(v[t], f);
      #pragma unroll
      for (int q = 0; q < 4; ++q) acc[q] = fmaf(dr[t], f[q], acc[q]);
    }
  }
  for (; e + 3 < end; e += 4) {
    int r[4];
    #pragma unroll
    for (int t = 0; t < 4; ++t) r[t] = sorted_row[e + t];
    float dr[4];
    uint2 v[4];
    #pragma unroll
    for (int t = 0; t < 4; ++t) {
      dr[t] = dinv[r[t]];
      v[t] = *(const uint2*)(hw + (size_t)r[t] * 128 + j);
    }
    #pragma unroll
    for (int t = 0; t < 4; ++t) {
      float f[4];
      bf4_unpack(v[t], f);
      #pragma unroll
      for (int q = 0; q < 4; ++q) acc[q] = fmaf(dr[t], f[q], acc[q]);
    }
  }
  for (; e < end; ++e) {
    const int r0 = sorted_row[e];
    const float d0 = dinv[r0];
    const uint2 v0 = *(const uint2*)(hw + (size_t)r0 * 128 + j);
    float f[4];
    bf4_unpack(v0, f);
    #pragma unroll
    for (int q = 0; q < 4; ++q) acc[q] = fmaf(d0, f[q], acc[q]);
  }

  const float4 bb = *(const float4*)(bias + j);
  const float o0 = fmaxf(fmaf(dc, acc[0], bb.x), 0.f);
  const float o1 = fmaxf(fmaf(dc, acc[1], bb.y), 0.f);
  const float o2 = fmaxf(fmaf(dc, acc[2], bb.z), 0.f);
  const float o3 = fmaxf(fmaf(dc, acc[3], bb.w), 0.f);
  uint2 st;
  st.x = bfpack(o0, o1);
  st.y = bfpack(o2, o3);
  *(uint2*)(hcat + (size_t)g * 384 + koff + j) = st;
}

extern "C" void kernel_launch(void* const* d_in, const int* in_sizes, int n_in,
                              void* d_out, int out_size, void* d_ws, size_t ws_size,
                              hipStream_t stream) {
  const float* x    = (const float*)d_in[0];
  const int*   ei   = (const int*)d_in[1];
  const float* W1   = (const float*)d_in[2];
  const float* b1   = (const float*)d_in[3];
  const float* W2   = (const float*)d_in[4];
  const float* b2   = (const float*)d_in[5];
  const float* W3   = (const float*)d_in[6];
  const float* b3   = (const float*)d_in[7];
  const float* Wlin = (const float*)d_in[8];
  const float* blin = (const float*)d_in[9];

  const int N = in_sizes[0] / 128;
  const int E = in_sizes[1] / 2;
  const int* rowi = ei;
  const int* coli = ei + E;

  // ws: degi | cursor | dinv | offs | bsums | sorted_row | WT* | hw | hcat
  char* ws = (char*)d_ws;
  const size_t nb4 = (((size_t)N * 4) + 255) & ~(size_t)255;
  int*   degi       = (int*)ws;                 ws += nb4;
  int*   cursor     = (int*)ws;                 ws += nb4;
  float* dinv       = (float*)ws;               ws += nb4;
  int*   offs       = (int*)ws;                 ws += nb4;
  int*   bsums      = (int*)ws;                 ws += 1024;
  int*   sorted_row = (int*)ws;                 ws += (((size_t)E * 4) + 255) & ~(size_t)255;
  unsigned short* WT1  = (unsigned short*)ws;   ws += 128 * 128 * 2;
  unsigned short* WT2  = (unsigned short*)ws;   ws += 128 * 128 * 2;
  unsigned short* WT3  = (unsigned short*)ws;   ws += 128 * 128 * 2;
  unsigned short* WTL  = (unsigned short*)ws;   ws += 64 * 384 * 2;
  unsigned short* hw   = (unsigned short*)ws;   ws += (size_t)N * 128 * 2;
  unsigned short* hcat = (unsigned short*)ws;

  const int nblk = (N + 1023) / 1024;  // <= 128
  const int gemmBlocks = (N + 127) / 128;
  const int nCh = (E + 8191) / 8192;   // edge chunks of 8192
  const int partBlocks = nCh * 8;      // x8 XCD ranges
  const int aggBlocks  = (N + 7) / 8;

  k_wt<<<(49152 + 24576 + 255) / 256, 256, 0, stream>>>(W1, W2, W3, Wlin,
                                                        WT1, WT2, WT3, WTL);
  hipMemsetAsync(degi, 0, (size_t)N * 4, stream);
  k_mega0<<<gemmBlocks + partBlocks, 256, 0, stream>>>(x, WT1, hw, N, gemmBlocks,
                                                       coli, E, degi);
  k_scan1<<<nblk, 256, 0, stream>>>(degi, N, offs, bsums, dinv);
  k_scan3f<<<nblk, 256, 0, stream>>>(offs, bsums, cursor, nblk, N);
  k_fill<<<partBlocks, 256, 0, stream>>>(rowi, coli, cursor, sorted_row, E, N);

  k_agg<<<aggBlocks, 256, 0, stream>>>(offs, degi, sorted_row, dinv, hw,
                                       b1, hcat, 0, N);
  k_gemm_mfma<<<gemmBlocks, 256, 0, stream>>>(hcat, 384, WT2, hw, N);
  k_agg<<<aggBlocks, 256, 0, stream>>>(offs, degi, sorted_row, dinv, hw,
                                       b2, hcat, 128, N);
  k_gemm_mfma<<<gemmBlocks, 256, 0, stream>>>(hcat + 128, 384, WT3, hw, N);
  k_agg<<<aggBlocks, 256, 0, stream>>>(offs, degi, sorted_row, dinv, hw,
                                       b3, hcat, 256, N);
  k_final_mfma<<<gemmBlocks, 256, 0, stream>>>(hcat, WTL, blin, (float*)d_out, N);
}